// Round 1
// baseline (332.251 us; speedup 1.0000x reference)
//
#include <hip/hip_runtime.h>
#include <hip/hip_bf16.h>

// Problem constants (fixed by setup_inputs): bs=4, S=1024, d_model=512, HEAD=8, D_Q=64
#define BS 4
#define SEQ 1024
#define DM 512
#define NQK 1024            // Q cols (512) + K cols (512) in fused GEMM output
#define NROW (BS*SEQ)       // 4096 GEMM rows
#define EPS 1e-9f
#define SQRTEPS 3.16227766e-5f

typedef __attribute__((ext_vector_type(8))) short short8;   // 8 bf16 (4 VGPRs)
typedef __attribute__((ext_vector_type(4))) float floatx4;  // MFMA C/D frag

// ---------------------------------------------------------------------------
// Kernel 1: f32 -> bf16 conversion (context, and Wq||Wk concatenated)
// ---------------------------------------------------------------------------
__global__ __launch_bounds__(256) void convert_kernel(
    const float* __restrict__ ctx, const float* __restrict__ Wq,
    const float* __restrict__ Wk, unsigned short* __restrict__ Xbf,
    unsigned short* __restrict__ Wbf)
{
    int idx = blockIdx.x * 256 + threadIdx.x;   // grid covers 2,097,152 exactly
    {
        unsigned int u = __float_as_uint(ctx[idx]);
        Xbf[idx] = (unsigned short)((u + 0x7fffu + ((u >> 16) & 1u)) >> 16);
    }
    if (idx < DM * DM) {   // 262144 weight elements each
        unsigned int a = __float_as_uint(Wq[idx]);
        Wbf[idx] = (unsigned short)((a + 0x7fffu + ((a >> 16) & 1u)) >> 16);
        unsigned int c = __float_as_uint(Wk[idx]);
        Wbf[DM * DM + idx] = (unsigned short)((c + 0x7fffu + ((c >> 16) & 1u)) >> 16);
    }
}

// ---------------------------------------------------------------------------
// Kernel 2: bf16 MFMA GEMM.  QK[m][n] = sum_k X[m][k] * W[n][k]  + bias[n]
//   X: 4096x512 bf16 (row-major), W: 1024x512 bf16 (row-major, N x K = "B^T")
//   QK: 4096x1024 f32.  cols [0,512) = Q, [512,1024) = K.
// 128x128 block tile, BK=32, 4 waves in 2x2, each wave 64x64 via 4x4 MFMAs.
// ---------------------------------------------------------------------------
#define BM 128
#define BN 128
#define BK 32
#define LDA 40   // padded LDS leading dim (ushorts): 32 + 8 to spread banks

__global__ __launch_bounds__(256) void gemm_qk(
    const unsigned short* __restrict__ X, const unsigned short* __restrict__ W,
    const float* __restrict__ bq, const float* __restrict__ bk,
    float* __restrict__ QK)
{
    __shared__ unsigned short As[BM * LDA];
    __shared__ unsigned short Bs[BN * LDA];

    const int tid  = threadIdx.x;
    const int bm   = blockIdx.x;          // 0..31
    const int bn   = blockIdx.y;          // 0..7
    const int wave = tid >> 6;
    const int lane = tid & 63;
    const int wm   = wave >> 1, wn = wave & 1;
    const int lr   = lane & 15;           // row/col within 16
    const int kg   = lane >> 4;           // k-group 0..3

    floatx4 acc[4][4] = {};

    for (int k0 = 0; k0 < DM; k0 += BK) {
        __syncthreads();
        // stage 128x32 of A and B; 512 chunks of 8 bf16 each; 2 chunks/thread/matrix
        #pragma unroll
        for (int p = 0; p < 2; ++p) {
            int c   = tid + p * 256;      // 0..511
            int row = c >> 2;
            int kc  = (c & 3) << 3;
            uint4 va = *(const uint4*)(X + (size_t)(bm * BM + row) * DM + k0 + kc);
            *(uint4*)(As + row * LDA + kc) = va;
            uint4 vb = *(const uint4*)(W + (size_t)(bn * BN + row) * DM + k0 + kc);
            *(uint4*)(Bs + row * LDA + kc) = vb;
        }
        __syncthreads();

        short8 a[4], b[4];
        #pragma unroll
        for (int mi = 0; mi < 4; ++mi)
            a[mi] = *(const short8*)(As + (wm * 64 + mi * 16 + lr) * LDA + kg * 8);
        #pragma unroll
        for (int ni = 0; ni < 4; ++ni)
            b[ni] = *(const short8*)(Bs + (wn * 64 + ni * 16 + lr) * LDA + kg * 8);
        #pragma unroll
        for (int mi = 0; mi < 4; ++mi)
            #pragma unroll
            for (int ni = 0; ni < 4; ++ni)
                acc[mi][ni] = __builtin_amdgcn_mfma_f32_16x16x32_bf16(
                    a[mi], b[ni], acc[mi][ni], 0, 0, 0);
    }

    // epilogue: C/D mapping col = lane&15, row = (lane>>4)*4 + reg
    #pragma unroll
    for (int mi = 0; mi < 4; ++mi) {
        #pragma unroll
        for (int ni = 0; ni < 4; ++ni) {
            int n = bn * BN + wn * 64 + ni * 16 + lr;
            float bias = (n < DM) ? bq[n] : bk[n - DM];
            #pragma unroll
            for (int r = 0; r < 4; ++r) {
                int m = bm * BM + wm * 64 + mi * 16 + kg * 4 + r;
                QK[(size_t)m * NQK + n] = acc[mi][ni][r] + bias;
            }
        }
    }
}

// ---------------------------------------------------------------------------
// Kernel 3: per-(b,h) tridiagonal softmax + log prefix-sum.
//   u[i] = q_i . k_{i+1} / 512, v[i] = q_{i+1} . k_i / 512   (i < S-1)
//   s_up[i]=s[i][i+1], s_dn[i]=s[i+1][i]; g[i]=sqrt(s_up*s_dn+eps)
//   C[i] = sum_{j<i} log(g[j]+eps)  (double-precision Hillis-Steele scan)
// One block of 1024 threads per (b,h); 32 blocks.
// ---------------------------------------------------------------------------
__global__ __launch_bounds__(1024) void scan_kernel(
    const float* __restrict__ QK, const int* __restrict__ am,
    float* __restrict__ gArr, float* __restrict__ CArr)
{
    __shared__ float uS[SEQ], vS[SEQ];
    __shared__ double sc[SEQ];

    const int bh = blockIdx.x;            // 0..31
    const int b  = bh >> 3, h = bh & 7;
    const int i  = threadIdx.x;           // 0..1023

    float u = 0.f, v = 0.f;
    if (i < SEQ - 1) {
        const floatx4* qi  = (const floatx4*)(QK + (size_t)(b * SEQ + i)     * NQK + h * 64);
        const floatx4* ki1 = (const floatx4*)(QK + (size_t)(b * SEQ + i + 1) * NQK + DM + h * 64);
        const floatx4* qi1 = (const floatx4*)(QK + (size_t)(b * SEQ + i + 1) * NQK + h * 64);
        const floatx4* ki  = (const floatx4*)(QK + (size_t)(b * SEQ + i)     * NQK + DM + h * 64);
        float su = 0.f, sv = 0.f;
        #pragma unroll
        for (int t = 0; t < 16; ++t) {
            floatx4 a = qi[t], c = ki1[t], d = qi1[t], e = ki[t];
            su += a.x * c.x + a.y * c.y + a.z * c.z + a.w * c.w;
            sv += d.x * e.x + d.y * e.y + d.z * e.z + d.w * e.w;
        }
        u = su * (1.0f / DM);
        v = sv * (1.0f / DM);
    }
    uS[i] = u; vS[i] = v;
    __syncthreads();

    float g = 0.f;
    if (i < SEQ - 1) {
        // row i: left neighbor j=i-1 (val vS[i-1]), right j=i+1 (val u)
        int mL = (i > 0) ? am[b * SEQ + i - 1] : 0;
        int mR = am[b * SEQ + i + 1];
        float s_up = mR ? (mL ? 1.f / (1.f + expf(vS[i - 1] - u)) : 1.f) : 0.f;
        // row i+1: left j=i (val v), right j=i+2 (val uS[i+1])
        int mL2 = am[b * SEQ + i];
        int mR2 = (i + 2 < SEQ) ? am[b * SEQ + i + 2] : 0;
        float s_dn = mL2 ? (mR2 ? 1.f / (1.f + expf(uS[i + 1] - v)) : 1.f) : 0.f;
        g = sqrtf(s_up * s_dn + EPS);
        gArr[bh * SEQ + i] = g;
    }

    double x = (i < SEQ - 1) ? (double)logf(g + EPS) : 0.0;
    sc[i] = x;
    __syncthreads();
    #pragma unroll
    for (int off = 1; off < SEQ; off <<= 1) {
        double t = (i >= off) ? sc[i - off] : 0.0;
        __syncthreads();
        sc[i] += t;
        __syncthreads();
    }
    CArr[bh * SEQ + i] = (i == 0) ? 0.f : (float)sc[i - 1];
}

// ---------------------------------------------------------------------------
// Kernel 4: output fill. One block per (bh,i) row; writes 1024 attn + 1024
// phrasal floats via float4.
//   attn[i][k] = k==i ? sqrt(eps) : exp(C[max]-C[min]) + 1e-9
//   phrasal[i][k] = k==i-1 ? g[i-1] : k==i+1 ? g[i] : sqrt(eps)
// ---------------------------------------------------------------------------
__global__ __launch_bounds__(256) void fill_kernel(
    const float* __restrict__ gArr, const float* __restrict__ CArr,
    float* __restrict__ attn, float* __restrict__ phrasal)
{
    const int row = blockIdx.x;           // bh*1024 + i, 0..32767
    const int bh  = row >> 10;
    const int i   = row & 1023;
    const int t   = threadIdx.x;

    const float Ci  = CArr[row];
    const float gm1 = (i > 0)       ? gArr[bh * SEQ + i - 1] : 0.f;
    const float gp  = (i < SEQ - 1) ? gArr[bh * SEQ + i]     : 0.f;

    floatx4 c4 = *(const floatx4*)(CArr + bh * SEQ + t * 4);
    floatx4 av, pv;
    #pragma unroll
    for (int j = 0; j < 4; ++j) {
        int k = t * 4 + j;
        float ck = c4[j];
        float d  = (k > i) ? (ck - Ci) : (Ci - ck);
        av[j] = (k == i) ? SQRTEPS : (__expf(d) + EPS);
        pv[j] = (k == i - 1) ? gm1 : ((k == i + 1) ? gp : SQRTEPS);
    }
    *(floatx4*)(attn    + (size_t)row * SEQ + t * 4) = av;
    *(floatx4*)(phrasal + (size_t)row * SEQ + t * 4) = pv;
}

// ---------------------------------------------------------------------------
extern "C" void kernel_launch(void* const* d_in, const int* in_sizes, int n_in,
                              void* d_out, int out_size, void* d_ws, size_t ws_size,
                              hipStream_t stream) {
    const float* ctx = (const float*)d_in[0];
    const int*   am  = (const int*)d_in[1];
    const float* Wq  = (const float*)d_in[2];
    const float* bq  = (const float*)d_in[3];
    const float* Wk  = (const float*)d_in[4];
    const float* bk  = (const float*)d_in[5];
    float* out = (float*)d_out;

    char* ws = (char*)d_ws;
    unsigned short* Xbf = (unsigned short*)(ws);                 //  4 MiB: 4096x512 bf16
    unsigned short* Wbf = (unsigned short*)(ws + 4194304);       //  1 MiB: 1024x512 bf16
    float*          QK  = (float*)(ws + 5242880);                // 16 MiB: 4096x1024 f32
    float*          gA  = (float*)(ws + 22020096);               // 128 KiB: 32x1024
    float*          CA  = (float*)(ws + 22151168);               // 128 KiB: 32x1024

    convert_kernel<<<dim3(BS * SEQ * DM / 256), 256, 0, stream>>>(ctx, Wq, Wk, Xbf, Wbf);
    gemm_qk<<<dim3(NROW / BM, NQK / BN), 256, 0, stream>>>(Xbf, Wbf, bq, bk, QK);
    scan_kernel<<<dim3(BS * 8), 1024, 0, stream>>>(QK, am, gA, CA);

    float* attn_out    = out;                       // 33,554,432 floats
    float* phrasal_out = out + (size_t)BS * 8 * SEQ * SEQ;
    fill_kernel<<<dim3(BS * 8 * SEQ), 256, 0, stream>>>(gA, CA, attn_out, phrasal_out);
}

// Round 2
// 300.887 us; speedup vs baseline: 1.1042x; 1.1042x over previous
//
#include <hip/hip_runtime.h>
#include <hip/hip_bf16.h>

// Problem constants (fixed by setup_inputs): bs=4, S=1024, d_model=512, HEAD=8, D_Q=64
#define BS 4
#define SEQ 1024
#define DM 512
#define NQK 1024            // Q cols (512) + K cols (512) in fused GEMM output
#define NROW (BS*SEQ)       // 4096 GEMM rows
#define EPS 1e-9f
#define SQRTEPS 3.16227766e-5f

typedef __attribute__((ext_vector_type(8))) short short8;   // 8 bf16 (4 VGPRs)
typedef __attribute__((ext_vector_type(4))) float floatx4;  // MFMA C/D frag

// ---------------------------------------------------------------------------
// Kernel 1: f32 -> bf16 conversion (context, and Wq||Wk concatenated)
// ---------------------------------------------------------------------------
__global__ __launch_bounds__(256) void convert_kernel(
    const float* __restrict__ ctx, const float* __restrict__ Wq,
    const float* __restrict__ Wk, unsigned short* __restrict__ Xbf,
    unsigned short* __restrict__ Wbf)
{
    int idx = blockIdx.x * 256 + threadIdx.x;   // grid covers 2,097,152 exactly
    {
        unsigned int u = __float_as_uint(ctx[idx]);
        Xbf[idx] = (unsigned short)((u + 0x7fffu + ((u >> 16) & 1u)) >> 16);
    }
    if (idx < DM * DM) {   // 262144 weight elements each
        unsigned int a = __float_as_uint(Wq[idx]);
        Wbf[idx] = (unsigned short)((a + 0x7fffu + ((a >> 16) & 1u)) >> 16);
        unsigned int c = __float_as_uint(Wk[idx]);
        Wbf[DM * DM + idx] = (unsigned short)((c + 0x7fffu + ((c >> 16) & 1u)) >> 16);
    }
}

// ---------------------------------------------------------------------------
// Kernel 2: bf16 MFMA GEMM.  QK[m][n] = sum_k X[m][k] * W[n][k] + bias[n]
// 64x64 block tile (4 blocks/CU, 16 waves/CU for latency hiding), BK=32,
// 4 waves in 2x2, each wave 32x32 via 2x2 MFMAs of 16x16x32.
// ---------------------------------------------------------------------------
#define BM 64
#define BN 64
#define BK 32
#define LDA 40   // padded LDS leading dim (ushorts); row stride 80 B keeps 16B align

__global__ __launch_bounds__(256) void gemm_qk(
    const unsigned short* __restrict__ X, const unsigned short* __restrict__ W,
    const float* __restrict__ bq, const float* __restrict__ bk,
    float* __restrict__ QK)
{
    __shared__ unsigned short As[BM * LDA];
    __shared__ unsigned short Bs[BN * LDA];

    const int tid  = threadIdx.x;
    const int bm   = blockIdx.x;          // 0..63
    const int bn   = blockIdx.y;          // 0..15
    const int wave = tid >> 6;
    const int lane = tid & 63;
    const int wm   = wave >> 1, wn = wave & 1;
    const int lr   = lane & 15;           // row/col within 16
    const int kg   = lane >> 4;           // k-group 0..3

    // staging: 256 chunks of 8 bf16 per matrix; thread t handles chunk t
    const int srow = tid >> 2;            // 0..63
    const int skc  = (tid & 3) << 3;      // 0,8,16,24
    const unsigned short* Xp = X + (size_t)(bm * BM + srow) * DM + skc;
    const unsigned short* Wp = W + (size_t)(bn * BN + srow) * DM + skc;

    floatx4 acc[2][2] = {};

    for (int k0 = 0; k0 < DM; k0 += BK) {
        // issue global loads before the barrier so latency overlaps the wait
        uint4 va = *(const uint4*)(Xp + k0);
        uint4 vb = *(const uint4*)(Wp + k0);
        __syncthreads();
        *(uint4*)(As + srow * LDA + skc) = va;
        *(uint4*)(Bs + srow * LDA + skc) = vb;
        __syncthreads();

        short8 a[2], b[2];
        #pragma unroll
        for (int mi = 0; mi < 2; ++mi)
            a[mi] = *(const short8*)(As + (wm * 32 + mi * 16 + lr) * LDA + kg * 8);
        #pragma unroll
        for (int ni = 0; ni < 2; ++ni)
            b[ni] = *(const short8*)(Bs + (wn * 32 + ni * 16 + lr) * LDA + kg * 8);
        #pragma unroll
        for (int mi = 0; mi < 2; ++mi)
            #pragma unroll
            for (int ni = 0; ni < 2; ++ni)
                acc[mi][ni] = __builtin_amdgcn_mfma_f32_16x16x32_bf16(
                    a[mi], b[ni], acc[mi][ni], 0, 0, 0);
    }

    // epilogue: C/D mapping col = lane&15, row = (lane>>4)*4 + reg
    #pragma unroll
    for (int mi = 0; mi < 2; ++mi) {
        #pragma unroll
        for (int ni = 0; ni < 2; ++ni) {
            int n = bn * BN + wn * 32 + ni * 16 + lr;
            float bias = (n < DM) ? bq[n] : bk[n - DM];
            #pragma unroll
            for (int r = 0; r < 4; ++r) {
                int m = bm * BM + wm * 32 + mi * 16 + kg * 4 + r;
                QK[(size_t)m * NQK + n] = acc[mi][ni][r] + bias;
            }
        }
    }
}

// ---------------------------------------------------------------------------
// Kernel 3: neighbor dots. One wave per (bh,i):
//   u[i] = q_i . k_{i+1} / 512,  v[i] = q_{i+1} . k_i / 512   (0 at i=S-1)
// 64-lane shuffle reduction; full-GPU parallelism (8192 blocks).
// ---------------------------------------------------------------------------
__global__ __launch_bounds__(256) void dot_kernel(
    const float* __restrict__ QK, float* __restrict__ uArr, float* __restrict__ vArr)
{
    const int gw   = blockIdx.x * 4 + (threadIdx.x >> 6);   // 0..32767 = bh*1024+i
    const int lane = threadIdx.x & 63;
    const int bh   = gw >> 10;
    const int i    = gw & 1023;
    const int b    = bh >> 3, h = bh & 7;

    float u = 0.f, v = 0.f;
    if (i < SEQ - 1) {
        const float* r0 = QK + (size_t)(b * SEQ + i)     * NQK;
        const float* r1 = QK + (size_t)(b * SEQ + i + 1) * NQK;
        float qi  = r0[h * 64 + lane];
        float ki  = r0[DM + h * 64 + lane];
        float qi1 = r1[h * 64 + lane];
        float ki1 = r1[DM + h * 64 + lane];
        float pu = qi * ki1, pv = qi1 * ki;
        #pragma unroll
        for (int m = 1; m < 64; m <<= 1) {
            pu += __shfl_xor(pu, m);
            pv += __shfl_xor(pv, m);
        }
        u = pu * (1.0f / DM);
        v = pv * (1.0f / DM);
    }
    if (lane == 0) { uArr[gw] = u; vArr[gw] = v; }
}

// ---------------------------------------------------------------------------
// Kernel 4: tridiagonal softmax -> g, then exclusive prefix-sum of log(g+eps)
// via wave-level double shuffles (1 barrier). One block of 1024 per (b,h).
// ---------------------------------------------------------------------------
__global__ __launch_bounds__(1024) void gscan_kernel(
    const float* __restrict__ uArr, const float* __restrict__ vArr,
    const int* __restrict__ am, float* __restrict__ gArr, float* __restrict__ CArr)
{
    __shared__ double wsum[16];

    const int bh   = blockIdx.x;          // 0..31
    const int b    = bh >> 3;
    const int i    = threadIdx.x;         // 0..1023
    const int base = bh * SEQ;

    float g = 0.f;
    if (i < SEQ - 1) {
        float u   = uArr[base + i];
        float vv  = vArr[base + i];
        int   im1 = (i > 0) ? i - 1 : 0;
        float vm1 = vArr[base + im1];
        float up1 = uArr[base + i + 1];
        // row i: left j=i-1 (v[i-1]) masked by am[i-1], right j=i+1 (u[i]) by am[i+1]
        int mL = (i > 0) ? am[b * SEQ + i - 1] : 0;
        int mR = am[b * SEQ + i + 1];
        float s_up = mR ? (mL ? 1.f / (1.f + expf(vm1 - u)) : 1.f) : 0.f;
        // row i+1: left j=i (v[i]) by am[i], right j=i+2 (u[i+1]) by am[i+2]
        int mL2 = am[b * SEQ + i];
        int mR2 = (i + 2 < SEQ) ? am[b * SEQ + i + 2] : 0;
        float s_dn = mL2 ? (mR2 ? 1.f / (1.f + expf(up1 - vv)) : 1.f) : 0.f;
        g = sqrtf(s_up * s_dn + EPS);
        gArr[base + i] = g;
    }

    double L = (i < SEQ - 1) ? (double)logf(g + EPS) : 0.0;
    double x = L;
    const int lane = i & 63, wv = i >> 6;
    #pragma unroll
    for (int off = 1; off < 64; off <<= 1) {
        double t = __shfl_up(x, off);
        if (lane >= off) x += t;
    }
    if (lane == 63) wsum[wv] = x;
    __syncthreads();
    double pref = 0.0;
    for (int w = 0; w < wv; ++w) pref += wsum[w];
    CArr[base + i] = (float)(pref + x - L);   // exclusive prefix: sum_{j<i} L[j]
}

// ---------------------------------------------------------------------------
// Kernel 5: output fill. One block per (bh,i) row; writes 1024 attn + 1024
// phrasal floats via float4.
//   attn[i][k] = k==i ? sqrt(eps) : exp(C[max]-C[min]) + 1e-9
//   phrasal[i][k] = k==i-1 ? g[i-1] : k==i+1 ? g[i] : sqrt(eps)
// ---------------------------------------------------------------------------
__global__ __launch_bounds__(256) void fill_kernel(
    const float* __restrict__ gArr, const float* __restrict__ CArr,
    float* __restrict__ attn, float* __restrict__ phrasal)
{
    const int row = blockIdx.x;           // bh*1024 + i, 0..32767
    const int bh  = row >> 10;
    const int i   = row & 1023;
    const int t   = threadIdx.x;

    const float Ci  = CArr[row];
    const float gm1 = (i > 0)       ? gArr[bh * SEQ + i - 1] : 0.f;
    const float gp  = (i < SEQ - 1) ? gArr[bh * SEQ + i]     : 0.f;

    floatx4 c4 = *(const floatx4*)(CArr + bh * SEQ + t * 4);
    floatx4 av, pv;
    #pragma unroll
    for (int j = 0; j < 4; ++j) {
        int k = t * 4 + j;
        float ck = c4[j];
        float d  = (k > i) ? (ck - Ci) : (Ci - ck);
        av[j] = (k == i) ? SQRTEPS : (__expf(d) + EPS);
        pv[j] = (k == i - 1) ? gm1 : ((k == i + 1) ? gp : SQRTEPS);
    }
    *(floatx4*)(attn    + (size_t)row * SEQ + t * 4) = av;
    *(floatx4*)(phrasal + (size_t)row * SEQ + t * 4) = pv;
}

// ---------------------------------------------------------------------------
extern "C" void kernel_launch(void* const* d_in, const int* in_sizes, int n_in,
                              void* d_out, int out_size, void* d_ws, size_t ws_size,
                              hipStream_t stream) {
    const float* ctx = (const float*)d_in[0];
    const int*   am  = (const int*)d_in[1];
    const float* Wq  = (const float*)d_in[2];
    const float* bq  = (const float*)d_in[3];
    const float* Wk  = (const float*)d_in[4];
    const float* bk  = (const float*)d_in[5];
    float* out = (float*)d_out;

    char* ws = (char*)d_ws;
    unsigned short* Xbf = (unsigned short*)(ws);                 //  4 MiB: 4096x512 bf16
    unsigned short* Wbf = (unsigned short*)(ws + 4194304);       //  1 MiB: 1024x512 bf16
    float*          QK  = (float*)(ws + 5242880);                // 16 MiB: 4096x1024 f32
    float*          uA  = (float*)(ws + 22020096);               // 128 KiB: 32x1024
    float*          vA  = (float*)(ws + 22151168);               // 128 KiB
    float*          gA  = (float*)(ws + 22282240);               // 128 KiB
    float*          CA  = (float*)(ws + 22413312);               // 128 KiB

    convert_kernel<<<dim3(BS * SEQ * DM / 256), 256, 0, stream>>>(ctx, Wq, Wk, Xbf, Wbf);
    gemm_qk<<<dim3(NROW / BM, NQK / BN), 256, 0, stream>>>(Xbf, Wbf, bq, bk, QK);
    dot_kernel<<<dim3(BS * 8 * SEQ / 4), 256, 0, stream>>>(QK, uA, vA);
    gscan_kernel<<<dim3(BS * 8), 1024, 0, stream>>>(uA, vA, am, gA, CA);

    float* attn_out    = out;                       // 33,554,432 floats
    float* phrasal_out = out + (size_t)BS * 8 * SEQ * SEQ;
    fill_kernel<<<dim3(BS * 8 * SEQ), 256, 0, stream>>>(gA, CA, attn_out, phrasal_out);
}

// Round 3
// 293.565 us; speedup vs baseline: 1.1318x; 1.0249x over previous
//
#include <hip/hip_runtime.h>
#include <hip/hip_bf16.h>

// Problem constants (fixed by setup_inputs): bs=4, S=1024, d_model=512, HEAD=8, D_Q=64
#define BS 4
#define SEQ 1024
#define DM 512
#define NQK 1024            // Q cols (512) + K cols (512) in fused GEMM output
#define NROW (BS*SEQ)       // 4096 GEMM rows
#define EPS 1e-9f
#define SQRTEPS 3.16227766e-5f

typedef __attribute__((ext_vector_type(8))) short short8;   // 8 bf16 (4 VGPRs)
typedef __attribute__((ext_vector_type(4))) float floatx4;  // MFMA C/D frag

// ---------------------------------------------------------------------------
// Kernel 1: f32 -> bf16 conversion (context, and Wq||Wk concatenated)
// ---------------------------------------------------------------------------
__global__ __launch_bounds__(256) void convert_kernel(
    const float* __restrict__ ctx, const float* __restrict__ Wq,
    const float* __restrict__ Wk, unsigned short* __restrict__ Xbf,
    unsigned short* __restrict__ Wbf)
{
    int idx = blockIdx.x * 256 + threadIdx.x;   // grid covers 2,097,152 exactly
    {
        unsigned int u = __float_as_uint(ctx[idx]);
        Xbf[idx] = (unsigned short)((u + 0x7fffu + ((u >> 16) & 1u)) >> 16);
    }
    if (idx < DM * DM) {   // 262144 weight elements each
        unsigned int a = __float_as_uint(Wq[idx]);
        Wbf[idx] = (unsigned short)((a + 0x7fffu + ((a >> 16) & 1u)) >> 16);
        unsigned int c = __float_as_uint(Wk[idx]);
        Wbf[DM * DM + idx] = (unsigned short)((c + 0x7fffu + ((c >> 16) & 1u)) >> 16);
    }
}

// ---------------------------------------------------------------------------
// Kernel 2: bf16 MFMA GEMM + concurrent phrasal-background fill.
//   Blocks [0,1024): QK[m][n] = sum_k X[m][k]*W[n][k] + bias[n]
//     64x64 tile, BK=32, 4 waves 2x2, wave does 32x32 via 2x2 MFMA 16x16x32.
//   Blocks [1024,5120): write sqrt(eps) background into phrasal (134 MB).
//     GEMM is MFMA/latency-bound with idle HBM write BW -> overlap hides ~21us.
// ---------------------------------------------------------------------------
#define BM 64
#define BN 64
#define BK 32
#define LDA 40      // padded LDS leading dim (ushorts); 80 B stride, 2-way banks = free
#define NGEMM 1024
#define NBG   4096  // 4096 blocks x 32 KiB = 134,217,728 B = full phrasal

__global__ __launch_bounds__(256) void gemm_qk_bg(
    const unsigned short* __restrict__ X, const unsigned short* __restrict__ W,
    const float* __restrict__ bq, const float* __restrict__ bk,
    float* __restrict__ QK, float* __restrict__ phrasal)
{
    __shared__ unsigned short As[BM * LDA];
    __shared__ unsigned short Bs[BN * LDA];

    const int id  = blockIdx.x;
    const int tid = threadIdx.x;

    if (id >= NGEMM) {               // -------- background writer block --------
        const int bb = id - NGEMM;   // 0..4095, covers 8192 floats each
        float* base = phrasal + (size_t)bb * 8192;
        floatx4 v4 = {SQRTEPS, SQRTEPS, SQRTEPS, SQRTEPS};
        #pragma unroll
        for (int j = 0; j < 8; ++j)
            *(floatx4*)(base + (size_t)(j * 256 + tid) * 4) = v4;
        return;
    }

    // ---------------- GEMM block ----------------
    const int bm   = id & 63;            // 0..63
    const int bn   = id >> 6;            // 0..15
    const int wave = tid >> 6;
    const int lane = tid & 63;
    const int wm   = wave >> 1, wn = wave & 1;
    const int lr   = lane & 15;          // row/col within 16
    const int kg   = lane >> 4;          // k-group 0..3

    // staging: 256 chunks of 8 bf16 per matrix; thread t handles chunk t
    const int srow = tid >> 2;           // 0..63
    const int skc  = (tid & 3) << 3;     // 0,8,16,24
    const unsigned short* Xp = X + (size_t)(bm * BM + srow) * DM + skc;
    const unsigned short* Wp = W + (size_t)(bn * BN + srow) * DM + skc;

    floatx4 acc[2][2] = {};

    for (int k0 = 0; k0 < DM; k0 += BK) {
        // issue global loads before the barrier so latency overlaps the wait
        uint4 va = *(const uint4*)(Xp + k0);
        uint4 vb = *(const uint4*)(Wp + k0);
        __syncthreads();
        *(uint4*)(As + srow * LDA + skc) = va;
        *(uint4*)(Bs + srow * LDA + skc) = vb;
        __syncthreads();

        short8 a[2], b[2];
        #pragma unroll
        for (int mi = 0; mi < 2; ++mi)
            a[mi] = *(const short8*)(As + (wm * 32 + mi * 16 + lr) * LDA + kg * 8);
        #pragma unroll
        for (int ni = 0; ni < 2; ++ni)
            b[ni] = *(const short8*)(Bs + (wn * 32 + ni * 16 + lr) * LDA + kg * 8);
        #pragma unroll
        for (int mi = 0; mi < 2; ++mi)
            #pragma unroll
            for (int ni = 0; ni < 2; ++ni)
                acc[mi][ni] = __builtin_amdgcn_mfma_f32_16x16x32_bf16(
                    a[mi], b[ni], acc[mi][ni], 0, 0, 0);
    }

    // epilogue: C/D mapping col = lane&15, row = (lane>>4)*4 + reg
    #pragma unroll
    for (int mi = 0; mi < 2; ++mi) {
        #pragma unroll
        for (int ni = 0; ni < 2; ++ni) {
            int n = bn * BN + wn * 32 + ni * 16 + lr;
            float bias = (n < DM) ? bq[n] : bk[n - DM];
            #pragma unroll
            for (int r = 0; r < 4; ++r) {
                int m = bm * BM + wm * 32 + mi * 16 + kg * 4 + r;
                QK[(size_t)m * NQK + n] = acc[mi][ni][r] + bias;
            }
        }
    }
}

// ---------------------------------------------------------------------------
// Kernel 3: neighbor dots. One wave per (bh,i):
//   u[i] = q_i . k_{i+1} / 512,  v[i] = q_{i+1} . k_i / 512   (0 at i=S-1)
// ---------------------------------------------------------------------------
__global__ __launch_bounds__(256) void dot_kernel(
    const float* __restrict__ QK, float* __restrict__ uArr, float* __restrict__ vArr)
{
    const int gw   = blockIdx.x * 4 + (threadIdx.x >> 6);   // 0..32767 = bh*1024+i
    const int lane = threadIdx.x & 63;
    const int bh   = gw >> 10;
    const int i    = gw & 1023;
    const int b    = bh >> 3, h = bh & 7;

    float u = 0.f, v = 0.f;
    if (i < SEQ - 1) {
        const float* r0 = QK + (size_t)(b * SEQ + i)     * NQK;
        const float* r1 = QK + (size_t)(b * SEQ + i + 1) * NQK;
        float qi  = r0[h * 64 + lane];
        float ki  = r0[DM + h * 64 + lane];
        float qi1 = r1[h * 64 + lane];
        float ki1 = r1[DM + h * 64 + lane];
        float pu = qi * ki1, pv = qi1 * ki;
        #pragma unroll
        for (int m = 1; m < 64; m <<= 1) {
            pu += __shfl_xor(pu, m);
            pv += __shfl_xor(pv, m);
        }
        u = pu * (1.0f / DM);
        v = pv * (1.0f / DM);
    }
    if (lane == 0) { uArr[gw] = u; vArr[gw] = v; }
}

// ---------------------------------------------------------------------------
// Kernel 4: tridiagonal softmax -> g, then exclusive prefix-sum of log(g+eps)
// via wave-level double shuffles (1 barrier). One block of 1024 per (b,h).
// ---------------------------------------------------------------------------
__global__ __launch_bounds__(1024) void gscan_kernel(
    const float* __restrict__ uArr, const float* __restrict__ vArr,
    const int* __restrict__ am, float* __restrict__ gArr, float* __restrict__ CArr)
{
    __shared__ double wsum[16];

    const int bh   = blockIdx.x;          // 0..31
    const int b    = bh >> 3;
    const int i    = threadIdx.x;         // 0..1023
    const int base = bh * SEQ;

    float g = 0.f;
    if (i < SEQ - 1) {
        float u   = uArr[base + i];
        float vv  = vArr[base + i];
        int   im1 = (i > 0) ? i - 1 : 0;
        float vm1 = vArr[base + im1];
        float up1 = uArr[base + i + 1];
        int mL = (i > 0) ? am[b * SEQ + i - 1] : 0;
        int mR = am[b * SEQ + i + 1];
        float s_up = mR ? (mL ? 1.f / (1.f + expf(vm1 - u)) : 1.f) : 0.f;
        int mL2 = am[b * SEQ + i];
        int mR2 = (i + 2 < SEQ) ? am[b * SEQ + i + 2] : 0;
        float s_dn = mL2 ? (mR2 ? 1.f / (1.f + expf(up1 - vv)) : 1.f) : 0.f;
        g = sqrtf(s_up * s_dn + EPS);
        gArr[base + i] = g;
    }

    double L = (i < SEQ - 1) ? (double)logf(g + EPS) : 0.0;
    double x = L;
    const int lane = i & 63, wv = i >> 6;
    #pragma unroll
    for (int off = 1; off < 64; off <<= 1) {
        double t = __shfl_up(x, off);
        if (lane >= off) x += t;
    }
    if (lane == 63) wsum[wv] = x;
    __syncthreads();
    double pref = 0.0;
    for (int w = 0; w < wv; ++w) pref += wsum[w];
    CArr[base + i] = (float)(pref + x - L);   // exclusive prefix: sum_{j<i} L[j]
}

// ---------------------------------------------------------------------------
// Kernel 5: attn fill + phrasal off-diagonal fix-up. One block per (bh,i) row.
//   attn[i][k] = k==i ? sqrt(eps) : exp(C[max]-C[min]) + 1e-9   (float4 row)
//   phrasal[i][i-1] = g[i-1], phrasal[i][i+1] = g[i]   (2 scalar stores;
//   background sqrt(eps) already written by gemm_qk_bg's writer blocks)
// ---------------------------------------------------------------------------
__global__ __launch_bounds__(256) void fill_attn(
    const float* __restrict__ gArr, const float* __restrict__ CArr,
    float* __restrict__ attn, float* __restrict__ phrasal)
{
    const int row = blockIdx.x;           // bh*1024 + i, 0..32767
    const int bh  = row >> 10;
    const int i   = row & 1023;
    const int t   = threadIdx.x;

    const float Ci = CArr[row];
    floatx4 c4 = *(const floatx4*)(CArr + bh * SEQ + t * 4);
    floatx4 av;
    #pragma unroll
    for (int j = 0; j < 4; ++j) {
        int k = t * 4 + j;
        float d = (k > i) ? (c4[j] - Ci) : (Ci - c4[j]);
        av[j] = (k == i) ? SQRTEPS : (__expf(d) + EPS);
    }
    *(floatx4*)(attn + (size_t)row * SEQ + t * 4) = av;

    if (t == 0) {
        if (i > 0)
            phrasal[(size_t)row * SEQ + i - 1] = gArr[bh * SEQ + i - 1];
        if (i < SEQ - 1)
            phrasal[(size_t)row * SEQ + i + 1] = gArr[bh * SEQ + i];
    }
}

// ---------------------------------------------------------------------------
extern "C" void kernel_launch(void* const* d_in, const int* in_sizes, int n_in,
                              void* d_out, int out_size, void* d_ws, size_t ws_size,
                              hipStream_t stream) {
    const float* ctx = (const float*)d_in[0];
    const int*   am  = (const int*)d_in[1];
    const float* Wq  = (const float*)d_in[2];
    const float* bq  = (const float*)d_in[3];
    const float* Wk  = (const float*)d_in[4];
    const float* bk  = (const float*)d_in[5];
    float* out = (float*)d_out;

    char* ws = (char*)d_ws;
    unsigned short* Xbf = (unsigned short*)(ws);                 //  4 MiB: 4096x512 bf16
    unsigned short* Wbf = (unsigned short*)(ws + 4194304);       //  1 MiB: 1024x512 bf16
    float*          QK  = (float*)(ws + 5242880);                // 16 MiB: 4096x1024 f32
    float*          uA  = (float*)(ws + 22020096);               // 128 KiB: 32x1024
    float*          vA  = (float*)(ws + 22151168);               // 128 KiB
    float*          gA  = (float*)(ws + 22282240);               // 128 KiB
    float*          CA  = (float*)(ws + 22413312);               // 128 KiB

    float* attn_out    = out;                       // 33,554,432 floats
    float* phrasal_out = out + (size_t)BS * 8 * SEQ * SEQ;

    convert_kernel<<<dim3(BS * SEQ * DM / 256), 256, 0, stream>>>(ctx, Wq, Wk, Xbf, Wbf);
    gemm_qk_bg<<<dim3(NGEMM + NBG), 256, 0, stream>>>(Xbf, Wbf, bq, bk, QK, phrasal_out);
    dot_kernel<<<dim3(BS * 8 * SEQ / 4), 256, 0, stream>>>(QK, uA, vA);
    gscan_kernel<<<dim3(BS * 8), 1024, 0, stream>>>(uA, vA, am, gA, CA);
    fill_attn<<<dim3(BS * 8 * SEQ), 256, 0, stream>>>(gA, CA, attn_out, phrasal_out);
}

// Round 4
// 291.422 us; speedup vs baseline: 1.1401x; 1.0074x over previous
//
#include <hip/hip_runtime.h>
#include <hip/hip_bf16.h>

// Problem constants (fixed by setup_inputs): bs=4, S=1024, d_model=512, HEAD=8, D_Q=64
#define BS 4
#define SEQ 1024
#define DM 512
#define NQK 1024            // Q cols (512) + K cols (512) in fused GEMM output
#define NROW (BS*SEQ)       // 4096 GEMM rows
#define EPS 1e-9f
#define SQRTEPS 3.16227766e-5f

typedef __attribute__((ext_vector_type(8))) short short8;   // 8 bf16 (4 VGPRs)
typedef __attribute__((ext_vector_type(4))) float floatx4;  // MFMA C/D frag

// phrasal background (134 MB = 4096 x 8192 floats) split across dispatches:
#define BG_GEMM 2560   // blocks in gemm dispatch   (83.9 MB, hides under MFMA)
#define BG_DOT  1024   // blocks in dot dispatch    (33.6 MB)
#define BG_SCAN 512    // blocks in gscan dispatch  (16.8 MB)

// ---------------------------------------------------------------------------
// Kernel 1: f32 -> bf16 conversion (context, and Wq||Wk concatenated)
// ---------------------------------------------------------------------------
__global__ __launch_bounds__(256) void convert_kernel(
    const float* __restrict__ ctx, const float* __restrict__ Wq,
    const float* __restrict__ Wk, unsigned short* __restrict__ Xbf,
    unsigned short* __restrict__ Wbf)
{
    int idx = blockIdx.x * 256 + threadIdx.x;   // grid covers 2,097,152 exactly
    {
        unsigned int u = __float_as_uint(ctx[idx]);
        Xbf[idx] = (unsigned short)((u + 0x7fffu + ((u >> 16) & 1u)) >> 16);
    }
    if (idx < DM * DM) {   // 262144 weight elements each
        unsigned int a = __float_as_uint(Wq[idx]);
        Wbf[idx] = (unsigned short)((a + 0x7fffu + ((a >> 16) & 1u)) >> 16);
        unsigned int c = __float_as_uint(Wk[idx]);
        Wbf[DM * DM + idx] = (unsigned short)((c + 0x7fffu + ((c >> 16) & 1u)) >> 16);
    }
}

// ---------------------------------------------------------------------------
// Kernel 2: bf16 MFMA GEMM + concurrent phrasal-background fill (2560 blocks).
//   Blocks [0,1024): QK[m][n] = sum_k X[m][k]*W[n][k] + bias[n]
//     64x64 tile, BK=64 (8 K-iters, 8 MFMA/iter/wave), 4 waves 2x2.
// ---------------------------------------------------------------------------
#define BM 64
#define BN 64
#define BK 64
#define LDA 72      // padded LDS leading dim (ushorts): 64 + 8; 2-way banks = free
#define NGEMM 1024

__global__ __launch_bounds__(256) void gemm_qk_bg(
    const unsigned short* __restrict__ X, const unsigned short* __restrict__ W,
    const float* __restrict__ bq, const float* __restrict__ bk,
    float* __restrict__ QK, float* __restrict__ phrasal)
{
    __shared__ unsigned short As[BM * LDA];
    __shared__ unsigned short Bs[BN * LDA];

    const int id  = blockIdx.x;
    const int tid = threadIdx.x;

    if (id >= NGEMM) {               // -------- background writer block --------
        const int bb = id - NGEMM;   // 0..2559, 8192 floats (32 KiB) each
        float* base = phrasal + (size_t)bb * 8192;
        floatx4 v4 = {SQRTEPS, SQRTEPS, SQRTEPS, SQRTEPS};
        #pragma unroll
        for (int j = 0; j < 8; ++j)
            *(floatx4*)(base + (size_t)(j * 256 + tid) * 4) = v4;
        return;
    }

    // ---------------- GEMM block ----------------
    const int bm   = id & 63;            // 0..63
    const int bn   = id >> 6;            // 0..15
    const int wave = tid >> 6;
    const int lane = tid & 63;
    const int wm   = wave >> 1, wn = wave & 1;
    const int lr   = lane & 15;          // row/col within 16
    const int kg   = lane >> 4;          // k-group 0..3

    // staging: 512 chunks of 8 bf16 per matrix; thread t handles chunks t, t+256
    const int srow = tid >> 3;           // 0..31
    const int skc  = (tid & 7) << 3;     // 0,8,...,56
    const unsigned short* Xp = X + (size_t)(bm * BM + srow) * DM + skc;
    const unsigned short* Wp = W + (size_t)(bn * BN + srow) * DM + skc;

    floatx4 acc[2][2] = {};

    for (int k0 = 0; k0 < DM; k0 += BK) {
        // issue global loads before the barrier so latency overlaps the wait
        uint4 va0 = *(const uint4*)(Xp + k0);
        uint4 va1 = *(const uint4*)(Xp + k0 + 32 * DM);
        uint4 vb0 = *(const uint4*)(Wp + k0);
        uint4 vb1 = *(const uint4*)(Wp + k0 + 32 * DM);
        __syncthreads();
        *(uint4*)(As + srow * LDA + skc)        = va0;
        *(uint4*)(As + (srow + 32) * LDA + skc) = va1;
        *(uint4*)(Bs + srow * LDA + skc)        = vb0;
        *(uint4*)(Bs + (srow + 32) * LDA + skc) = vb1;
        __syncthreads();

        #pragma unroll
        for (int ks = 0; ks < 2; ++ks) {
            short8 a[2], b[2];
            #pragma unroll
            for (int mi = 0; mi < 2; ++mi)
                a[mi] = *(const short8*)(As + (wm * 32 + mi * 16 + lr) * LDA + ks * 32 + kg * 8);
            #pragma unroll
            for (int ni = 0; ni < 2; ++ni)
                b[ni] = *(const short8*)(Bs + (wn * 32 + ni * 16 + lr) * LDA + ks * 32 + kg * 8);
            #pragma unroll
            for (int mi = 0; mi < 2; ++mi)
                #pragma unroll
                for (int ni = 0; ni < 2; ++ni)
                    acc[mi][ni] = __builtin_amdgcn_mfma_f32_16x16x32_bf16(
                        a[mi], b[ni], acc[mi][ni], 0, 0, 0);
        }
    }

    // epilogue: C/D mapping col = lane&15, row = (lane>>4)*4 + reg
    #pragma unroll
    for (int mi = 0; mi < 2; ++mi) {
        #pragma unroll
        for (int ni = 0; ni < 2; ++ni) {
            int n = bn * BN + wn * 32 + ni * 16 + lr;
            float bias = (n < DM) ? bq[n] : bk[n - DM];
            #pragma unroll
            for (int r = 0; r < 4; ++r) {
                int m = bm * BM + wm * 32 + mi * 16 + kg * 4 + r;
                QK[(size_t)m * NQK + n] = acc[mi][ni][r] + bias;
            }
        }
    }
}

// ---------------------------------------------------------------------------
// Kernel 3: neighbor dots + phrasal-background fill (1024 writer blocks).
//   u[i] = q_i . k_{i+1} / 512,  v[i] = q_{i+1} . k_i / 512   (0 at i=S-1)
// ---------------------------------------------------------------------------
#define NDOT 8192

__global__ __launch_bounds__(256) void dot_kernel(
    const float* __restrict__ QK, float* __restrict__ uArr, float* __restrict__ vArr,
    float* __restrict__ phrasal)
{
    const int id = blockIdx.x;
    if (id >= NDOT) {                // -------- background writer block --------
        const int bb = id - NDOT;    // 0..1023
        float* base = phrasal + (size_t)(BG_GEMM + bb) * 8192;
        floatx4 v4 = {SQRTEPS, SQRTEPS, SQRTEPS, SQRTEPS};
        #pragma unroll
        for (int j = 0; j < 8; ++j)
            *(floatx4*)(base + (size_t)(j * 256 + threadIdx.x) * 4) = v4;
        return;
    }

    const int gw   = id * 4 + (threadIdx.x >> 6);   // 0..32767 = bh*1024+i
    const int lane = threadIdx.x & 63;
    const int bh   = gw >> 10;
    const int i    = gw & 1023;
    const int b    = bh >> 3, h = bh & 7;

    float u = 0.f, v = 0.f;
    if (i < SEQ - 1) {
        const float* r0 = QK + (size_t)(b * SEQ + i)     * NQK;
        const float* r1 = QK + (size_t)(b * SEQ + i + 1) * NQK;
        float qi  = r0[h * 64 + lane];
        float ki  = r0[DM + h * 64 + lane];
        float qi1 = r1[h * 64 + lane];
        float ki1 = r1[DM + h * 64 + lane];
        float pu = qi * ki1, pv = qi1 * ki;
        #pragma unroll
        for (int m = 1; m < 64; m <<= 1) {
            pu += __shfl_xor(pu, m);
            pv += __shfl_xor(pv, m);
        }
        u = pu * (1.0f / DM);
        v = pv * (1.0f / DM);
    }
    if (lane == 0) { uArr[gw] = u; vArr[gw] = v; }
}

// ---------------------------------------------------------------------------
// Kernel 4: tridiagonal softmax -> g, exclusive prefix-sum of log(g+eps),
// + phrasal-background fill (512 writer blocks of 1024 threads).
// ---------------------------------------------------------------------------
__global__ __launch_bounds__(1024) void gscan_kernel(
    const float* __restrict__ uArr, const float* __restrict__ vArr,
    const int* __restrict__ am, float* __restrict__ gArr, float* __restrict__ CArr,
    float* __restrict__ phrasal)
{
    __shared__ double wsum[16];

    if (blockIdx.x >= 32) {          // -------- background writer block --------
        const int bb = blockIdx.x - 32;   // 0..511, 8192 floats each
        float* base = phrasal + (size_t)(BG_GEMM + BG_DOT + bb) * 8192;
        floatx4 v4 = {SQRTEPS, SQRTEPS, SQRTEPS, SQRTEPS};
        #pragma unroll
        for (int j = 0; j < 2; ++j)
            *(floatx4*)(base + (size_t)(j * 1024 + threadIdx.x) * 4) = v4;
        return;
    }

    const int bh   = blockIdx.x;          // 0..31
    const int b    = bh >> 3;
    const int i    = threadIdx.x;         // 0..1023
    const int base = bh * SEQ;

    float g = 0.f;
    if (i < SEQ - 1) {
        float u   = uArr[base + i];
        float vv  = vArr[base + i];
        int   im1 = (i > 0) ? i - 1 : 0;
        float vm1 = vArr[base + im1];
        float up1 = uArr[base + i + 1];
        int mL = (i > 0) ? am[b * SEQ + i - 1] : 0;
        int mR = am[b * SEQ + i + 1];
        float s_up = mR ? (mL ? 1.f / (1.f + expf(vm1 - u)) : 1.f) : 0.f;
        int mL2 = am[b * SEQ + i];
        int mR2 = (i + 2 < SEQ) ? am[b * SEQ + i + 2] : 0;
        float s_dn = mL2 ? (mR2 ? 1.f / (1.f + expf(up1 - vv)) : 1.f) : 0.f;
        g = sqrtf(s_up * s_dn + EPS);
        gArr[base + i] = g;
    }

    double L = (i < SEQ - 1) ? (double)logf(g + EPS) : 0.0;
    double x = L;
    const int lane = i & 63, wv = i >> 6;
    #pragma unroll
    for (int off = 1; off < 64; off <<= 1) {
        double t = __shfl_up(x, off);
        if (lane >= off) x += t;
    }
    if (lane == 63) wsum[wv] = x;
    __syncthreads();
    double pref = 0.0;
    for (int w = 0; w < wv; ++w) pref += wsum[w];
    CArr[base + i] = (float)(pref + x - L);   // exclusive prefix: sum_{j<i} L[j]
}

// ---------------------------------------------------------------------------
// Kernel 5: attn fill + phrasal off-diagonal fix-up. One block per (bh,i) row.
//   attn[i][k] = k==i ? sqrt(eps) : exp(C[max]-C[min]) + 1e-9   (float4 row)
//   phrasal[i][i-1] = g[i-1], phrasal[i][i+1] = g[i]
// ---------------------------------------------------------------------------
__global__ __launch_bounds__(256) void fill_attn(
    const float* __restrict__ gArr, const float* __restrict__ CArr,
    float* __restrict__ attn, float* __restrict__ phrasal)
{
    const int row = blockIdx.x;           // bh*1024 + i, 0..32767
    const int bh  = row >> 10;
    const int i   = row & 1023;
    const int t   = threadIdx.x;

    const float Ci = CArr[row];
    floatx4 c4 = *(const floatx4*)(CArr + bh * SEQ + t * 4);
    floatx4 av;
    #pragma unroll
    for (int j = 0; j < 4; ++j) {
        int k = t * 4 + j;
        float d = (k > i) ? (c4[j] - Ci) : (Ci - c4[j]);
        av[j] = (k == i) ? SQRTEPS : (__expf(d) + EPS);
    }
    *(floatx4*)(attn + (size_t)row * SEQ + t * 4) = av;

    if (t == 0) {
        if (i > 0)
            phrasal[(size_t)row * SEQ + i - 1] = gArr[bh * SEQ + i - 1];
        if (i < SEQ - 1)
            phrasal[(size_t)row * SEQ + i + 1] = gArr[bh * SEQ + i];
    }
}

// ---------------------------------------------------------------------------
extern "C" void kernel_launch(void* const* d_in, const int* in_sizes, int n_in,
                              void* d_out, int out_size, void* d_ws, size_t ws_size,
                              hipStream_t stream) {
    const float* ctx = (const float*)d_in[0];
    const int*   am  = (const int*)d_in[1];
    const float* Wq  = (const float*)d_in[2];
    const float* bq  = (const float*)d_in[3];
    const float* Wk  = (const float*)d_in[4];
    const float* bk  = (const float*)d_in[5];
    float* out = (float*)d_out;

    char* ws = (char*)d_ws;
    unsigned short* Xbf = (unsigned short*)(ws);                 //  4 MiB: 4096x512 bf16
    unsigned short* Wbf = (unsigned short*)(ws + 4194304);       //  1 MiB: 1024x512 bf16
    float*          QK  = (float*)(ws + 5242880);                // 16 MiB: 4096x1024 f32
    float*          uA  = (float*)(ws + 22020096);               // 128 KiB: 32x1024
    float*          vA  = (float*)(ws + 22151168);               // 128 KiB
    float*          gA  = (float*)(ws + 22282240);               // 128 KiB
    float*          CA  = (float*)(ws + 22413312);               // 128 KiB

    float* attn_out    = out;                       // 33,554,432 floats
    float* phrasal_out = out + (size_t)BS * 8 * SEQ * SEQ;

    convert_kernel<<<dim3(BS * SEQ * DM / 256), 256, 0, stream>>>(ctx, Wq, Wk, Xbf, Wbf);
    gemm_qk_bg<<<dim3(NGEMM + BG_GEMM), 256, 0, stream>>>(Xbf, Wbf, bq, bk, QK, phrasal_out);
    dot_kernel<<<dim3(NDOT + BG_DOT), 256, 0, stream>>>(QK, uA, vA, phrasal_out);
    gscan_kernel<<<dim3(32 + BG_SCAN), 1024, 0, stream>>>(uA, vA, am, gA, CA, phrasal_out);
    fill_attn<<<dim3(BS * 8 * SEQ), 256, 0, stream>>>(gA, CA, attn_out, phrasal_out);
}